// Round 1
// baseline (1242.563 us; speedup 1.0000x reference)
//
#include <hip/hip_runtime.h>
#include <hip/hip_bf16.h>

// Problem constants (LLaMA-7B-like FFN up-proj, blockwise int8 weight-only quant)
#define D_IN   4096
#define D_OUT  11008
#define NB     32
#define BLKQ   128
#define M_ROWS 8192          // B*S = 4*2048
#define KP     4160          // 4096 + 32 (xsum cols) + 32 (zero pad) = 65*64

// GEMM tiling (m97-structure: 128x128 tile, BK=64, 4 waves 2x2, 16x16x32 bf16 MFMA)
#define BM  128
#define BN  128
#define BK  64
#define NBM 64               // 8192/128
#define NBN 86               // 11008/128

typedef __attribute__((ext_vector_type(4))) float f32x4;
typedef __attribute__((ext_vector_type(8))) short bf16x8;

// f32 -> bf16 (RNE), pure bit ops (no dependency on hip_bf16 API quirks)
static __device__ __forceinline__ unsigned short f2bf(float f) {
  unsigned int u = __float_as_uint(f);
  unsigned int lsb = (u >> 16) & 1u;
  u += 0x7fffu + lsb;
  return (unsigned short)(u >> 16);
}

// ---------------------------------------------------------------------------
// Prepass A: x (f32 [M][4096]) -> A_ws (bf16 [M][4160])
//   cols 0..4095   : bf16(x)
//   cols 4096..4127: bf16(sum of 128-block)  (xsum, feeds the -zp rows of B)
//   cols 4128..4159: 0
// One 256-thread block per row.
__global__ void prep_a_kernel(const float* __restrict__ x,
                              unsigned short* __restrict__ A) {
  const int m = blockIdx.x;
  const int t = threadIdx.x;
  const float* xr = x + (size_t)m * D_IN;
  unsigned short* Ar = A + (size_t)m * KP;
  __shared__ float psum[1024];
#pragma unroll
  for (int i = 0; i < 4; ++i) {
    const int c4 = i * 256 + t;            // float4 index; block s = c4/32
    const float4 v = ((const float4*)xr)[c4];
    ushort4 o;
    o.x = f2bf(v.x); o.y = f2bf(v.y); o.z = f2bf(v.z); o.w = f2bf(v.w);
    ((ushort4*)Ar)[c4] = o;
    psum[c4] = v.x + v.y + v.z + v.w;
  }
  __syncthreads();
  if (t < 32) {                             // block t: float4 indices [32t, 32t+32)
    float s = 0.f;
    const int base = t * 32;
#pragma unroll
    for (int j = 0; j < 32; ++j) s += psum[base + j];
    Ar[D_IN + t] = f2bf(s);
  } else if (t < 64) {
    Ar[D_IN + t] = 0;                       // zero pad cols 4128..4159
  }
}

// ---------------------------------------------------------------------------
// Prepass B: weight (int32 [32][128][11008], n fastest) + scaler ([32][11008])
//   -> Bt (bf16 [11008][4160]) TRANSPOSED: Bt[n][k] = bf16(w[k][n]*scaler[k/128][n])
// 64x64 tile transpose via LDS. Each 64-k tile lies inside one quant block s.
__global__ void prep_b_kernel(const int* __restrict__ w,
                              const float* __restrict__ scaler,
                              unsigned short* __restrict__ Bt) {
  const int k0 = blockIdx.x * 64;           // 64 k-tiles
  const int n0 = blockIdx.y * 64;           // 172 n-tiles
  const int s  = k0 >> 7;
  const int t  = threadIdx.x;
  __shared__ unsigned short lds[64][66];    // pad 66: 2-way max on transpose read
  {
    const int nl = t & 63;                  // lanes along n -> coalesced reads
    const int kb = t >> 6;
    const float sc = scaler[(size_t)s * D_OUT + n0 + nl];
#pragma unroll
    for (int i = 0; i < 16; ++i) {
      const int kl = i * 4 + kb;
      const int wv = w[(size_t)(k0 + kl) * D_OUT + n0 + nl];
      lds[kl][nl] = f2bf((float)wv * sc);
    }
  }
  __syncthreads();
  {
    const int kl = t & 63;                  // lanes along k -> coalesced writes
    const int nb = t >> 6;
#pragma unroll
    for (int i = 0; i < 16; ++i) {
      const int nl = i * 4 + nb;
      Bt[(size_t)(n0 + nl) * KP + k0 + kl] = lds[kl][nl];
    }
  }
}

// Fill Bt rows k' = 4096..4159: 32 rows of -zp (zero-point correction as extra
// K-steps) + 32 zero rows.
__global__ void prep_zp_kernel(const float* __restrict__ zp,
                               unsigned short* __restrict__ Bt) {
  const int t = threadIdx.x;
  const int n = blockIdx.x * 4 + (t >> 6);
  const int kk = t & 63;                    // lanes along k -> coalesced writes
  const float v = (kk < NB) ? -zp[(size_t)kk * D_OUT + n] : 0.f;
  Bt[(size_t)n * KP + D_IN + kk] = f2bf(v);
}

// ---------------------------------------------------------------------------
// GEMM: C[M][N] = A[M][KP] * Bt[N][KP]^T   (both bf16, fp32 accum/out)
// m97 structure: 128x128 tile, BK=64, global_load_lds width-16 staging (linear
// LDS dest — T2 swizzle is null at 2-phase), 2 barriers/K-step, 32 MFMA/wave/step.
__global__ __launch_bounds__(256) void gemm_kernel(
    const unsigned short* __restrict__ A,
    const unsigned short* __restrict__ B,
    float* __restrict__ C) {
  __shared__ unsigned short As[BM * BK];    // [128 m][64 k] linear, 16 KiB
  __shared__ unsigned short Bs[BN * BK];    // [128 n][64 k] linear, 16 KiB
  const int t = threadIdx.x;
  const int lane = t & 63;
  const int w = t >> 6;
  const int wm = w >> 1, wn = w & 1;        // 2x2 wave grid, 64x64 out each

  // XCD-aware bijective swizzle (nwg = 5504, % 8 == 0)
  const int nwg = NBM * NBN;
  const int cpx = nwg >> 3;
  const int bid = blockIdx.x;
  const int swz = (bid & 7) * cpx + (bid >> 3);
  const int tm = swz / NBN;
  const int tn = swz - tm * NBN;

  const size_t m0 = (size_t)tm * BM;
  const size_t n0 = (size_t)tn * BN;
  const unsigned short* Ab = A + m0 * KP;
  const unsigned short* Bb = B + n0 * KP;

  f32x4 acc[4][4];
#pragma unroll
  for (int i = 0; i < 4; ++i)
#pragma unroll
    for (int j = 0; j < 4; ++j)
      acc[i][j] = (f32x4){0.f, 0.f, 0.f, 0.f};

  for (int k0 = 0; k0 < KP; k0 += BK) {
    // Stage A tile: 1024 granules of 16B; granule g -> row g/8, colgroup g%8.
    // LDS dest is wave-uniform base + lane*16 (linear), source is per-lane.
#pragma unroll
    for (int i = 0; i < 4; ++i) {
      const int g = i * 256 + t;
      const int row = g >> 3;
      const int cg = g & 7;
      const unsigned short* gp = Ab + (size_t)row * KP + k0 + cg * 8;
      char* lp = (char*)As + (size_t)(i * 256 + (t & 192)) * 16;
      __builtin_amdgcn_global_load_lds(
          (const __attribute__((address_space(1))) void*)gp,
          (__attribute__((address_space(3))) void*)lp, 16, 0, 0);
    }
#pragma unroll
    for (int i = 0; i < 4; ++i) {
      const int g = i * 256 + t;
      const int row = g >> 3;
      const int cg = g & 7;
      const unsigned short* gp = Bb + (size_t)row * KP + k0 + cg * 8;
      char* lp = (char*)Bs + (size_t)(i * 256 + (t & 192)) * 16;
      __builtin_amdgcn_global_load_lds(
          (const __attribute__((address_space(1))) void*)gp,
          (__attribute__((address_space(3))) void*)lp, 16, 0, 0);
    }
    __syncthreads();   // compiler emits vmcnt(0) drain before barrier

    bf16x8 af[2][4], bg[2][4];
#pragma unroll
    for (int ks = 0; ks < 2; ++ks) {
#pragma unroll
      for (int mf = 0; mf < 4; ++mf) {
        const int r = wm * 64 + mf * 16 + (lane & 15);
        af[ks][mf] = *(const bf16x8*)&As[r * BK + ks * 32 + (lane >> 4) * 8];
      }
#pragma unroll
      for (int nf = 0; nf < 4; ++nf) {
        const int r = wn * 64 + nf * 16 + (lane & 15);
        bg[ks][nf] = *(const bf16x8*)&Bs[r * BK + ks * 32 + (lane >> 4) * 8];
      }
    }
#pragma unroll
    for (int ks = 0; ks < 2; ++ks)
#pragma unroll
      for (int mf = 0; mf < 4; ++mf)
#pragma unroll
        for (int nf = 0; nf < 4; ++nf)
          acc[mf][nf] = __builtin_amdgcn_mfma_f32_16x16x32_bf16(
              af[ks][mf], bg[ks][nf], acc[mf][nf], 0, 0, 0);
    __syncthreads();   // protect LDS before next stage overwrites
  }

  // Epilogue: C/D layout col = lane&15, row = (lane>>4)*4 + j  [m89-verified]
#pragma unroll
  for (int mf = 0; mf < 4; ++mf) {
#pragma unroll
    for (int nf = 0; nf < 4; ++nf) {
      const size_t row = m0 + wm * 64 + mf * 16 + ((lane >> 4) << 2);
      const size_t col = n0 + wn * 64 + nf * 16 + (lane & 15);
      float* Cp = C + row * D_OUT + col;
#pragma unroll
      for (int j = 0; j < 4; ++j)
        Cp[(size_t)j * D_OUT] = acc[mf][nf][j];
    }
  }
}

// ---------------------------------------------------------------------------
extern "C" void kernel_launch(void* const* d_in, const int* in_sizes, int n_in,
                              void* d_out, int out_size, void* d_ws, size_t ws_size,
                              hipStream_t stream) {
  const float* x      = (const float*)d_in[0];  // [4][2048][4096] f32
  const int*   wq     = (const int*)  d_in[1];  // [32][128][11008] int32 (int8 vals)
  const float* scaler = (const float*)d_in[2];  // [32][11008] f32
  const float* zp     = (const float*)d_in[3];  // [32][11008] f32
  float* out = (float*)d_out;                   // [8192][11008] f32

  // Workspace: A (bf16 [8192][4160]) then Bt (bf16 [11008][4160]) = 152.3 MB
  unsigned short* A  = (unsigned short*)d_ws;
  unsigned short* Bt = A + (size_t)M_ROWS * KP;

  prep_a_kernel<<<M_ROWS, 256, 0, stream>>>(x, A);
  prep_b_kernel<<<dim3(D_IN / 64, D_OUT / 64), 256, 0, stream>>>(wq, scaler, Bt);
  prep_zp_kernel<<<D_OUT / 4, 256, 0, stream>>>(zp, Bt);
  gemm_kernel<<<NBM * NBN, 256, 0, stream>>>(A, Bt, out);
}

// Round 2
// 760.006 us; speedup vs baseline: 1.6349x; 1.6349x over previous
//
#include <hip/hip_runtime.h>
#include <hip/hip_bf16.h>

// Problem constants
#define D_IN   4096
#define D_OUT  11008
#define NB     32
#define M_ROWS 8192
#define KP     4160          // 4096 + 32 (xsum) + 32 (pad) = 65*64
#define NT     65            // K-tiles of 64

// GEMM tiling: 256x256 tile, BK=64, 8 waves (2m x 4n), 8-phase schedule
#define BM  256
#define BN  256
#define BK  64
#define NBM 32               // 8192/256
#define NBN 43               // 11008/256

typedef __attribute__((ext_vector_type(4))) float f32x4;
typedef __attribute__((ext_vector_type(8))) short bf16x8;

static __device__ __forceinline__ unsigned short f2bf(float f) {
  unsigned int u = __float_as_uint(f);
  unsigned int lsb = (u >> 16) & 1u;
  u += 0x7fffu + lsb;
  return (unsigned short)(u >> 16);
}

// ---------------------------------------------------------------------------
// Prepass A (unchanged, proven): x f32 [M][4096] -> A bf16 [M][4160]
__global__ void prep_a_kernel(const float* __restrict__ x,
                              unsigned short* __restrict__ A) {
  const int m = blockIdx.x;
  const int t = threadIdx.x;
  const float* xr = x + (size_t)m * D_IN;
  unsigned short* Ar = A + (size_t)m * KP;
  __shared__ float psum[1024];
#pragma unroll
  for (int i = 0; i < 4; ++i) {
    const int c4 = i * 256 + t;
    const float4 v = ((const float4*)xr)[c4];
    ushort4 o;
    o.x = f2bf(v.x); o.y = f2bf(v.y); o.z = f2bf(v.z); o.w = f2bf(v.w);
    ((ushort4*)Ar)[c4] = o;
    psum[c4] = v.x + v.y + v.z + v.w;
  }
  __syncthreads();
  if (t < 32) {
    float s = 0.f;
    const int base = t * 32;
#pragma unroll
    for (int j = 0; j < 32; ++j) s += psum[base + j];
    Ar[D_IN + t] = f2bf(s);
  } else if (t < 64) {
    Ar[D_IN + t] = 0;
  }
}

// Prepass B (unchanged, proven): w int32 [32][128][11008] -> Bt bf16 [11008][4160]
__global__ void prep_b_kernel(const int* __restrict__ w,
                              const float* __restrict__ scaler,
                              unsigned short* __restrict__ Bt) {
  const int k0 = blockIdx.x * 64;
  const int n0 = blockIdx.y * 64;
  const int s  = k0 >> 7;
  const int t  = threadIdx.x;
  __shared__ unsigned short lds[64][66];
  {
    const int nl = t & 63;
    const int kb = t >> 6;
    const float sc = scaler[(size_t)s * D_OUT + n0 + nl];
#pragma unroll
    for (int i = 0; i < 16; ++i) {
      const int kl = i * 4 + kb;
      const int wv = w[(size_t)(k0 + kl) * D_OUT + n0 + nl];
      lds[kl][nl] = f2bf((float)wv * sc);
    }
  }
  __syncthreads();
  {
    const int kl = t & 63;
    const int nb = t >> 6;
#pragma unroll
    for (int i = 0; i < 16; ++i) {
      const int nl = i * 4 + nb;
      Bt[(size_t)(n0 + nl) * KP + k0 + kl] = lds[kl][nl];
    }
  }
}

__global__ void prep_zp_kernel(const float* __restrict__ zp,
                               unsigned short* __restrict__ Bt) {
  const int t = threadIdx.x;
  const int n = blockIdx.x * 4 + (t >> 6);
  const int kk = t & 63;
  const float v = (kk < NB) ? -zp[(size_t)kk * D_OUT + n] : 0.f;
  Bt[(size_t)n * KP + D_IN + kk] = f2bf(v);
}

// ---------------------------------------------------------------------------
// 8-phase 256^2 GEMM (m201-style template, plain HIP).
// LDS: 2 dbuf x (A 256x64 + B 256x64) bf16 = 128 KiB. Even K-tiles -> buf0.
// Swizzle: 16B-granule index g XORed with (row&7); applied to the global
// SOURCE column in staging (linear gload_lds dest) and to the ds_read addr.
// Staging: 8 quarters (64 rows) per K-tile, 1 gload_lds x16B per thread per
// quarter, 2 quarters per phase. vmcnt(6) only at phases 4/8.
#define BAR()  __builtin_amdgcn_s_barrier()
#define PRIO1() __builtin_amdgcn_s_setprio(1)
#define PRIO0() __builtin_amdgcn_s_setprio(0)
#define VMW6() asm volatile("s_waitcnt vmcnt(6)" ::: "memory")
#define VMW8() asm volatile("s_waitcnt vmcnt(8)" ::: "memory")
#define VMW0() asm volatile("s_waitcnt vmcnt(0)" ::: "memory")

// Stage quarter q (rows q*64..q*64+63) of the tile at column kb from panel
// into LDS region (ushort* base of a 256x64 tile). Linear dest; source col
// pre-swizzled so that a swizzled read returns the linear element.
#define STQ(panelS, region, q, kb)                                             \
  do {                                                                         \
    const unsigned short* gp_ = (panelS) + (size_t)(q) * 64 * KP + (kb);       \
    unsigned short* lp_ = (region) + (q) * 4096 + (tid >> 6) * 512;            \
    __builtin_amdgcn_global_load_lds(                                          \
        (const __attribute__((address_space(1))) void*)gp_,                    \
        (__attribute__((address_space(3))) void*)lp_, 16, 0, 0);               \
  } while (0)

// Read A fragments for m-half QM from buffer BUFOFF (ushort offset)
#define RD_AF(BUFOFF, QM)                                                      \
  do {                                                                         \
    _Pragma("unroll") for (int mf = 0; mf < 4; ++mf) {                         \
      const int ro = ((QM) * 64 + mf * 16) * 64 + (BUFOFF);                    \
      af[0][mf] = *(const bf16x8*)(smem + aOff0 + ro);                         \
      af[1][mf] = *(const bf16x8*)(smem + aOff1 + ro);                         \
    }                                                                          \
  } while (0)

// Read B fragments for n-half QN into BG
#define RD_BG(BUFOFF, BG, QN)                                                  \
  do {                                                                         \
    _Pragma("unroll") for (int nf = 0; nf < 2; ++nf) {                         \
      const int ro = ((QN) * 32 + nf * 16) * 64 + 16384 + (BUFOFF);            \
      BG[0][nf] = *(const bf16x8*)(smem + bOff0 + ro);                         \
      BG[1][nf] = *(const bf16x8*)(smem + bOff1 + ro);                         \
    }                                                                          \
  } while (0)

// 16 MFMA: quadrant (QM,QN), K=64 (ks chained into same acc)
#define MM(QM, QN, BG)                                                         \
  do {                                                                         \
    _Pragma("unroll") for (int mf = 0; mf < 4; ++mf)                           \
    _Pragma("unroll") for (int nf = 0; nf < 2; ++nf) {                         \
      f32x4 c = acc[(QM) * 4 + mf][(QN) * 2 + nf];                             \
      c = __builtin_amdgcn_mfma_f32_16x16x32_bf16(af[0][mf], BG[0][nf], c, 0, 0, 0); \
      c = __builtin_amdgcn_mfma_f32_16x16x32_bf16(af[1][mf], BG[1][nf], c, 0, 0, 0); \
      acc[(QM) * 4 + mf][(QN) * 2 + nf] = c;                                   \
    }                                                                          \
  } while (0)

__global__ __launch_bounds__(512, 2) void gemm8_kernel(
    const unsigned short* __restrict__ A,
    const unsigned short* __restrict__ B,
    float* __restrict__ C) {
  __shared__ unsigned short smem[65536];   // 128 KiB: [buf][A|B][256][64]
  const int tid  = threadIdx.x;
  const int lane = tid & 63;
  const int w    = tid >> 6;
  const int wm   = w >> 2;                 // 0..1
  const int wn   = w & 3;                  // 0..3
  const int l15  = lane & 15;
  const int g    = lane >> 4;

  // XCD-aware bijective swizzle (nwg = 1376, %8 == 0)
  const int bid = blockIdx.x;
  const int swz = (bid & 7) * ((NBM * NBN) >> 3) + (bid >> 3);
  const int tm = swz / NBN;
  const int tn = swz - tm * NBN;
  const size_t m0 = (size_t)tm * BM;
  const size_t n0 = (size_t)tn * BN;

  // Staging source base: row = q*64 + (tid>>3); source granule = (tid&7)^(row&7)
  const int srow = tid >> 3;               // 0..63 within quarter
  const int sgr  = (tid & 7) ^ (srow & 7); // pre-swizzled source granule
  const unsigned short* ApS = A + (m0 + srow) * KP + sgr * 8;
  const unsigned short* BpS = B + (n0 + srow) * KP + sgr * 8;

  // ds_read offsets (ushort units): row*64 + swizzled-granule*8
  const int sg0 = ((g) ^ (lane & 7)) * 8;        // ks=0: granule g
  const int sg1 = ((4 + g) ^ (lane & 7)) * 8;    // ks=1: granule 4+g
  const int aOff0 = (wm * 128 + l15) * 64 + sg0;
  const int aOff1 = (wm * 128 + l15) * 64 + sg1;
  const int bOff0 = (wn * 64 + l15) * 64 + sg0;
  const int bOff1 = (wn * 64 + l15) * 64 + sg1;

  f32x4 acc[8][4];
#pragma unroll
  for (int i = 0; i < 8; ++i)
#pragma unroll
    for (int j = 0; j < 4; ++j) acc[i][j] = (f32x4){0.f, 0.f, 0.f, 0.f};
  bf16x8 af[2][4], bgA[2][2], bgB[2][2];

  // Prologue: fully stage tile 0 (buf0) then tile 1 (buf1); wait tile 0.
#pragma unroll
  for (int q = 0; q < 4; ++q) STQ(ApS, smem, q, 0);
#pragma unroll
  for (int q = 0; q < 4; ++q) STQ(BpS, smem + 16384, q, 0);
#pragma unroll
  for (int q = 0; q < 4; ++q) STQ(ApS, smem + 32768, q, 64);
#pragma unroll
  for (int q = 0; q < 4; ++q) STQ(BpS, smem + 49152, q, 64);
  VMW8();
  BAR();

#pragma unroll 1
  for (int i = 0; i < 32; ++i) {
    const int kn1 = 2 * i * 64 + 64;   // tile 2i+1 (buf1)
    const int kn2 = kn1 + 64;          // tile 2i+2 (buf0)
    const int kn3 = kn1 + 128;         // tile 2i+3 (buf1)
    const bool s3 = (i < 31);

    // P1: compute tile 2i Q(0,0); stage A-q1,q3 of 2i+1 -> buf1 (region last
    //     read at previous iteration's P7 — safe)
    RD_AF(0, 0); RD_BG(0, bgA, 0);
    STQ(ApS, smem + 32768, 1, kn1); STQ(ApS, smem + 32768, 3, kn1);
    BAR(); PRIO1(); MM(0, 0, bgA); PRIO0(); BAR();

    // P2: Q(0,1); stage A-q0,q2 of 2i+2 -> buf0 (read at P1)
    RD_BG(0, bgB, 1);
    STQ(ApS, smem, 0, kn2); STQ(ApS, smem, 2, kn2);
    BAR(); PRIO1(); MM(0, 1, bgB); PRIO0(); BAR();

    // P3: Q(1,0); stage B-q0,q1 of 2i+2 -> buf0 (B read at P1/P2)
    RD_AF(0, 1);
    STQ(BpS, smem + 16384, 0, kn2); STQ(BpS, smem + 16384, 1, kn2);
    BAR(); PRIO1(); MM(1, 0, bgA); PRIO0(); BAR();

    // P4: Q(1,1); stage B-q2,q3 of 2i+2; vmcnt(6) drains P1's pair -> tile
    //     2i+1 fully resident before P5
    STQ(BpS, smem + 16384, 2, kn2); STQ(BpS, smem + 16384, 3, kn2);
    BAR(); PRIO1(); MM(1, 1, bgB); PRIO0();
    VMW6(); BAR();

    // P5: compute tile 2i+1 (buf1) Q(0,0); stage A-q1,q3 of 2i+2 -> buf0
    //     (read at P3)
    RD_AF(32768, 0); RD_BG(32768, bgA, 0);
    STQ(ApS, smem, 1, kn2); STQ(ApS, smem, 3, kn2);
    BAR(); PRIO1(); MM(0, 0, bgA); PRIO0(); BAR();

    // P6: Q(0,1); stage A-q0,q2 of 2i+3 -> buf1 (read at P5)
    RD_BG(32768, bgB, 1);
    if (s3) { STQ(ApS, smem + 32768, 0, kn3); STQ(ApS, smem + 32768, 2, kn3); }
    BAR(); PRIO1(); MM(0, 1, bgB); PRIO0(); BAR();

    // P7: Q(1,0); stage B-q0,q1 of 2i+3 (B buf1 read at P5/P6)
    RD_AF(32768, 1);
    if (s3) { STQ(BpS, smem + 49152, 0, kn3); STQ(BpS, smem + 49152, 1, kn3); }
    BAR(); PRIO1(); MM(1, 0, bgA); PRIO0(); BAR();

    // P8: Q(1,1); stage B-q2,q3 of 2i+3; vmcnt(6) drains P5's pair -> tile
    //     2i+2 fully resident for next iteration's P1
    if (s3) { STQ(BpS, smem + 49152, 2, kn3); STQ(BpS, smem + 49152, 3, kn3); }
    BAR(); PRIO1(); MM(1, 1, bgB); PRIO0();
    VMW6(); BAR();
  }

  // Epilogue: tile 64 (buf0) — staged during the last iteration's P2..P5;
  // drain everything, then 4 compute phases with no staging.
  VMW0();
  BAR();
  RD_AF(0, 0); RD_BG(0, bgA, 0); MM(0, 0, bgA);
  RD_BG(0, bgB, 1);              MM(0, 1, bgB);
  RD_AF(0, 1);                   MM(1, 0, bgA);
                                 MM(1, 1, bgB);

  // C write: col = lane&15, row = (lane>>4)*4 + j (m89-verified layout)
#pragma unroll
  for (int mfi = 0; mfi < 8; ++mfi) {
#pragma unroll
    for (int nfi = 0; nfi < 4; ++nfi) {
      const size_t row = m0 + wm * 128 + mfi * 16 + (g << 2);
      const size_t col = n0 + wn * 64 + nfi * 16 + l15;
      float* Cp = C + row * D_OUT + col;
#pragma unroll
      for (int j = 0; j < 4; ++j) Cp[(size_t)j * D_OUT] = acc[mfi][nfi][j];
    }
  }
}

// ---------------------------------------------------------------------------
extern "C" void kernel_launch(void* const* d_in, const int* in_sizes, int n_in,
                              void* d_out, int out_size, void* d_ws, size_t ws_size,
                              hipStream_t stream) {
  const float* x      = (const float*)d_in[0];
  const int*   wq     = (const int*)  d_in[1];
  const float* scaler = (const float*)d_in[2];
  const float* zp     = (const float*)d_in[3];
  float* out = (float*)d_out;

  unsigned short* A  = (unsigned short*)d_ws;
  unsigned short* Bt = A + (size_t)M_ROWS * KP;

  prep_a_kernel<<<M_ROWS, 256, 0, stream>>>(x, A);
  prep_b_kernel<<<dim3(D_IN / 64, D_OUT / 64), 256, 0, stream>>>(wq, scaler, Bt);
  prep_zp_kernel<<<D_OUT / 4, 256, 0, stream>>>(zp, Bt);
  gemm8_kernel<<<NBM * NBN, 512, 0, stream>>>(A, Bt, out);
}